// Round 6
// baseline (427.115 us; speedup 1.0000x reference)
//
#include <hip/hip_runtime.h>
#include <math.h>

#define NN 131072
#define KK 27
#define FIN 3
#define FOUT 32
#define EPS 1e-5f

typedef _Float16 f16;
typedef __attribute__((ext_vector_type(8))) _Float16 f16x8;
typedef __attribute__((ext_vector_type(16))) float f32x16;

// ===========================================================================
// Device workers (shared by fused single-dispatch path and classic fallback)
// ===========================================================================

// Pack one spatial tap k of w2 (f32 [32][32]) into f16 MFMA B-fragments:
// w2p[k][half][lane][j]; B layout for v_mfma_f32_32x32x16:
// col = lane&31, kdim = (lane>>5)*8 + j.  (proven since round 1)
__device__ __forceinline__ void pack_w2_block(
    const float* __restrict__ w2, f16* __restrict__ w2p, int k, int t)
{
#pragma unroll
    for (int r = 0; r < 4; ++r) {
        const int e    = r * 256 + t;
        const int half = e >> 9;
        const int l    = (e >> 3) & 63;
        const int j    = e & 7;
        const int krow = half * 16 + ((l >> 5) << 3) + j;
        const int n    = l & 31;
        w2p[k * 1024 + e] = (f16)w2[k * (FOUT * FOUT) + krow * FOUT + n];
    }
}

// conv1 partial accumulate over taps [KB, KB+KN). Compile-time trip counts,
// no predication (round-2 lesson), idx hoist pinned per-value (rule #17).
template<int KB, int KN>
__device__ __forceinline__ void c1_accum(
    int n, const float* __restrict__ x, const int* __restrict__ nbr,
    const float* __restrict__ w1, float* acc)
{
    int idxs[KN];
    const int* nb = nbr + (size_t)n * KK + KB;
#pragma unroll
    for (int i = 0; i < KN; ++i) idxs[i] = nb[i];
#pragma unroll
    for (int i = 0; i < KN; ++i) asm volatile("" : "+v"(idxs[i]));

    constexpr int C0 = 7, C1 = KN - 7;
    float xs[7][3];
#pragma unroll
    for (int q = 0; q < C0; ++q) {
        const float* xr = x + (size_t)idxs[q] * FIN;
        xs[q][0] = xr[0]; xs[q][1] = xr[1]; xs[q][2] = xr[2];
    }
#pragma unroll
    for (int q = 0; q < C0; ++q) {
        const float* w = w1 + (KB + q) * (FIN * FOUT);   // input -> s_load safe
#pragma unroll
        for (int o = 0; o < FOUT; ++o)
            acc[o] = fmaf(xs[q][0], w[o],
                     fmaf(xs[q][1], w[FOUT + o],
                     fmaf(xs[q][2], w[2 * FOUT + o], acc[o])));
    }
#pragma unroll
    for (int q = 0; q < C1; ++q) {
        const float* xr = x + (size_t)idxs[C0 + q] * FIN;
        xs[q][0] = xr[0]; xs[q][1] = xr[1]; xs[q][2] = xr[2];
    }
#pragma unroll
    for (int q = 0; q < C1; ++q) {
        const float* w = w1 + (KB + C0 + q) * (FIN * FOUT);
#pragma unroll
        for (int o = 0; o < FOUT; ++o)
            acc[o] = fmaf(xs[q][0], w[o],
                     fmaf(xs[q][1], w[FOUT + o],
                     fmaf(xs[q][2], w[2 * FOUT + o], acc[o])));
    }
}

// conv1 for one 128-node chunk: 2-way k-split (t<128: k0..13, t>=128:
// k14..26), LDS reduce, BN+SiLU, store h [N][32] f16 (64-B rows = 1 line).
__device__ __forceinline__ void conv1_chunk(
    int chunk, int t,
    const float* __restrict__ x, const int* __restrict__ nbr,
    const float* __restrict__ w1,
    const float* __restrict__ g1, const float* __restrict__ b1,
    const float* __restrict__ m1, const float* __restrict__ v1,
    f16* __restrict__ h, float (*racc)[128])
{
    const int khalf = t >> 7;
    const int ln    = t & 127;
    const int n     = chunk * 128 + ln;

    float acc[FOUT];
#pragma unroll
    for (int o = 0; o < FOUT; ++o) acc[o] = 0.f;

    if (khalf == 0) c1_accum<0, 14>(n, x, nbr, w1, acc);
    else            c1_accum<14, 13>(n, x, nbr, w1, acc);

    if (khalf) {
#pragma unroll
        for (int o = 0; o < FOUT; ++o) racc[o][ln] = acc[o];
    }
    __syncthreads();
    if (!khalf) {
#pragma unroll
        for (int o = 0; o < FOUT; ++o) acc[o] += racc[o][ln];
        f16* hr = h + (size_t)n * FOUT;
#pragma unroll
        for (int g = 0; g < 4; ++g) {
            f16x8 hv;
#pragma unroll
            for (int j = 0; j < 8; ++j) {
                const int o = g * 8 + j;
                const float sc = g1[o] * rsqrtf(v1[o] + EPS);
                float v = (acc[o] - m1[o]) * sc + b1[o];
                v = v / (1.f + __expf(-v));              // silu
                hv[j] = (f16)v;
            }
            *(f16x8*)(hr + g * 8) = hv;
        }
    }
    __syncthreads();                     // LDS safe for next grid-stride chunk
}

// conv2 MFMA over taps [KB, KB+KN): round-1 proven inner loop (dual acc,
// depth-1 rotate, setprio), unified h rows (a1/a2 share one cache line).
template<int KB, int KN>
__device__ __forceinline__ void c2_half(
    int nrow, int hi, int lane, const f16* __restrict__ h,
    const int* __restrict__ nbr, const f16x8* __restrict__ bp,
    f32x16& acc0, f32x16& acc1)
{
    int idxs[KN];
    const int* nb = nbr + (size_t)nrow * KK + KB;
#pragma unroll
    for (int i = 0; i < KN; ++i) idxs[i] = nb[i];
#pragma unroll
    for (int i = 0; i < KN; ++i) asm volatile("" : "+v"(idxs[i]));

    const f16* hr0 = h + (size_t)idxs[0] * FOUT + hi * 8;
    f16x8 a1 = *(const f16x8*)hr0;
    f16x8 a2 = *(const f16x8*)(hr0 + 16);
    f16x8 b1 = bp[KB * 128 + lane];
    f16x8 b2 = bp[KB * 128 + 64 + lane];

#pragma unroll
    for (int i = 0; i < KN; ++i) {
        f16x8 na1, na2, nb1, nb2;
        if (i + 1 < KN) {
            const f16* hr = h + (size_t)idxs[i + 1] * FOUT + hi * 8;
            na1 = *(const f16x8*)hr;
            na2 = *(const f16x8*)(hr + 16);
            nb1 = bp[(KB + i + 1) * 128 + lane];
            nb2 = bp[(KB + i + 1) * 128 + 64 + lane];
        }
        __builtin_amdgcn_s_setprio(1);
        acc0 = __builtin_amdgcn_mfma_f32_32x32x16_f16(a1, b1, acc0, 0, 0, 0);
        acc1 = __builtin_amdgcn_mfma_f32_32x32x16_f16(a2, b2, acc1, 0, 0, 0);
        __builtin_amdgcn_s_setprio(0);
        if (i + 1 < KN) { a1 = na1; a2 = na2; b1 = nb1; b2 = nb2; }
    }
}

__device__ __forceinline__ void conv2_chunk(
    int chunk, int t, const f16* __restrict__ h, const int* __restrict__ nbr,
    const f16* __restrict__ w2p, const float* __restrict__ z,
    const float* __restrict__ mw, const float* __restrict__ mb2,
    const float* __restrict__ mg, const float* __restrict__ mbe,
    const float* __restrict__ mm, const float* __restrict__ mv,
    float* __restrict__ out)
{
    const int lane = t & 63;
    const int wave = t >> 6;
    const int base = chunk * 128 + wave * 32;
    const int row  = lane & 31;
    const int hi   = lane >> 5;

    f32x16 acc0 = {}, acc1 = {};
    const f16x8* bp = (const f16x8*)w2p;
    c2_half<0, 14>(base + row, hi, lane, h, nbr, bp, acc0, acc1);
    c2_half<14, 13>(base + row, hi, lane, h, nbr, bp, acc0, acc1);

    // ---- epilogue: point branch for column n0, fused add + dual store ----
    const int n0 = lane & 31;
    const float wc0 = mw[n0];
    const float wc1 = mw[FOUT + n0];
    const float wc2 = mw[2 * FOUT + n0];
    const float sc  = mg[n0] * rsqrtf(mv[n0] + EPS);
    const float bi  = mb2[n0];
    const float mmv = mm[n0];
    const float mbv = mbe[n0];

#pragma unroll
    for (int r = 0; r < 16; ++r) {
        const int m    = (r & 3) + ((r >> 2) << 3) + (hi << 2); // C/D row map
        const int node = base + m;
        const float* zr = z + (size_t)node * FIN;
        float zv = bi;
        zv = fmaf(zr[0], wc0, zv);
        zv = fmaf(zr[1], wc1, zv);
        zv = fmaf(zr[2], wc2, zv);
        zv = (zv - mmv) * sc + mbv;
        zv = fmaxf(zv, 0.f);
        const float v = acc0[r] + acc1[r] + zv;
        out[(size_t)node * FOUT + n0] = v;
        out[(size_t)NN * FOUT + (size_t)node * FOUT + n0] = v;
    }
}

// ---------------------------------------------------------------------------
// Grid barrier: monotonic counter in workspace, reset to 0 each replay by a
// captured hipMemsetAsync. Release-fence before arrival, acquire after.
// Safe because grid size G is taken from the occupancy API (all co-resident).
// ---------------------------------------------------------------------------
__device__ __forceinline__ void grid_bar(unsigned* bar, unsigned target)
{
    __threadfence();                  // release this thread's stores (agent)
    __syncthreads();                  // all threads' fences done
    if (threadIdx.x == 0) {
        __hip_atomic_fetch_add(bar, 1u, __ATOMIC_RELEASE,
                               __HIP_MEMORY_SCOPE_AGENT);
        while (__hip_atomic_load(bar, __ATOMIC_ACQUIRE,
                                 __HIP_MEMORY_SCOPE_AGENT) < target)
            __builtin_amdgcn_s_sleep(2);
    }
    __syncthreads();
    __threadfence();                  // acquire: invalidate vL1 before reads
}

// ===========================================================================
// Single-dispatch fused kernel: pack -> bar -> conv1 -> bar -> conv2
// ===========================================================================
__global__ __launch_bounds__(256, 4) void fused_kernel(
    const float* __restrict__ x, const float* __restrict__ z,
    const int* __restrict__ nbr, const float* __restrict__ w1,
    const float* __restrict__ g1, const float* __restrict__ b1,
    const float* __restrict__ m1, const float* __restrict__ v1,
    const float* __restrict__ w2,
    const float* __restrict__ mw, const float* __restrict__ mb2,
    const float* __restrict__ mg, const float* __restrict__ mbe,
    const float* __restrict__ mm, const float* __restrict__ mv,
    f16* __restrict__ h, f16* __restrict__ w2p, unsigned* __restrict__ bar,
    float* __restrict__ out)
{
    __shared__ float racc[FOUT][128];    // 16 KiB (conv1 phase only)
    const int t   = threadIdx.x;
    const int bid = blockIdx.x;
    const int G   = gridDim.x;
    const int NC  = NN / 128;

    for (int k = bid; k < KK; k += G) pack_w2_block(w2, w2p, k, t);
    grid_bar(bar, (unsigned)G);

    for (int c = bid; c < NC; c += G)
        conv1_chunk(c, t, x, nbr, w1, g1, b1, m1, v1, h, racc);
    grid_bar(bar, (unsigned)(2 * G));

    for (int c = bid; c < NC; c += G)
        conv2_chunk(c, t, h, nbr, w2p, z, mw, mb2, mg, mbe, mm, mv, out);
}

// ===========================================================================
// Classic 3-dispatch fallback (round-1 structure, same workers)
// ===========================================================================
__global__ __launch_bounds__(256) void pack_kernel(
    const float* __restrict__ w2, f16* __restrict__ w2p)
{
    if (blockIdx.x < KK) pack_w2_block(w2, w2p, blockIdx.x, threadIdx.x);
}

__global__ __launch_bounds__(256) void conv1_kernel(
    const float* __restrict__ x, const int* __restrict__ nbr,
    const float* __restrict__ w1,
    const float* __restrict__ g1, const float* __restrict__ b1,
    const float* __restrict__ m1, const float* __restrict__ v1,
    f16* __restrict__ h)
{
    __shared__ float racc[FOUT][128];
    conv1_chunk(blockIdx.x, threadIdx.x, x, nbr, w1, g1, b1, m1, v1, h, racc);
}

__global__ __launch_bounds__(256) void conv2_kernel(
    const f16* __restrict__ h, const int* __restrict__ nbr,
    const f16* __restrict__ w2p, const float* __restrict__ z,
    const float* __restrict__ mw, const float* __restrict__ mb2,
    const float* __restrict__ mg, const float* __restrict__ mbe,
    const float* __restrict__ mm, const float* __restrict__ mv,
    float* __restrict__ out)
{
    conv2_chunk(blockIdx.x, threadIdx.x, h, nbr, w2p, z,
                mw, mb2, mg, mbe, mm, mv, out);
}

extern "C" void kernel_launch(void* const* d_in, const int* in_sizes, int n_in,
                              void* d_out, int out_size, void* d_ws, size_t ws_size,
                              hipStream_t stream) {
    const float* x_feats = (const float*)d_in[0];
    const float* z_feats = (const float*)d_in[1];
    const int*   nbr_idx = (const int*)d_in[2];
    const float* w1      = (const float*)d_in[3];
    const float* bn1_g   = (const float*)d_in[4];
    const float* bn1_b   = (const float*)d_in[5];
    const float* bn1_m   = (const float*)d_in[6];
    const float* bn1_v   = (const float*)d_in[7];
    const float* w2      = (const float*)d_in[8];
    const float* mlp_w   = (const float*)d_in[9];
    const float* mlp_b   = (const float*)d_in[10];
    const float* mlp_g   = (const float*)d_in[11];
    const float* mlp_be  = (const float*)d_in[12];
    const float* mlp_m   = (const float*)d_in[13];
    const float* mlp_v   = (const float*)d_in[14];

    // workspace: h [0,8M)  w2p [8M, 8M+55296)  bar @ 9M   (ws >= 11M proven)
    const size_t OFF_W2P = (size_t)8 * 1024 * 1024;
    const size_t OFF_BAR = (size_t)9 * 1024 * 1024;

    f16*      h    = (f16*)d_ws;
    f16*      w2p  = (f16*)((char*)d_ws + OFF_W2P);
    unsigned* bar  = (unsigned*)((char*)d_ws + OFF_BAR);
    float*    out  = (float*)d_out;

    // Size the fused grid so every block is co-resident (barrier-safe).
    int maxB = 0;
    hipError_t oe = hipOccupancyMaxActiveBlocksPerMultiprocessor(
        &maxB, fused_kernel, 256, 0);
    int G = 0;
    if (oe == hipSuccess && maxB > 0) {
        G = maxB * 256;                     // 256 CUs on MI355X
        if (G > NN / 128) G = NN / 128;     // never need more than 1024
    }

    if (G >= 256 && ws_size >= OFF_BAR + 64) {
        hipMemsetAsync(bar, 0, sizeof(unsigned), stream);
        fused_kernel<<<G, 256, 0, stream>>>(
            x_feats, z_feats, nbr_idx, w1, bn1_g, bn1_b, bn1_m, bn1_v, w2,
            mlp_w, mlp_b, mlp_g, mlp_be, mlp_m, mlp_v, h, w2p, bar, out);
    } else {
        pack_kernel<<<KK, 256, 0, stream>>>(w2, w2p);
        conv1_kernel<<<NN / 128, 256, 0, stream>>>(
            x_feats, nbr_idx, w1, bn1_g, bn1_b, bn1_m, bn1_v, h);
        conv2_kernel<<<NN / 128, 256, 0, stream>>>(
            h, nbr_idx, w2p, z_feats, mlp_w, mlp_b, mlp_g, mlp_be,
            mlp_m, mlp_v, out);
    }
}

// Round 7
// 169.065 us; speedup vs baseline: 2.5263x; 2.5263x over previous
//
#include <hip/hip_runtime.h>
#include <math.h>

#define NN 131072
#define KK 27
#define FIN 3
#define FOUT 32
#define EPS 1e-5f

typedef _Float16 f16;
typedef __attribute__((ext_vector_type(8))) _Float16 f16x8;
typedef __attribute__((ext_vector_type(4)))  float   f32x4;
typedef __attribute__((ext_vector_type(16))) float   f32x16;

// ---------------------------------------------------------------------------
// Pack one spatial tap k of w2 (f32 [32][32]) into f16 MFMA B-fragments:
// w2p[k][half][lane][j]; B layout for v_mfma_f32_32x32x16:
// col = lane&31, kdim = (lane>>5)*8 + j.  (proven since round 1)
// ---------------------------------------------------------------------------
__device__ __forceinline__ void pack_w2_block(
    const float* __restrict__ w2, f16* __restrict__ w2p, int k, int t)
{
#pragma unroll
    for (int r = 0; r < 4; ++r) {
        const int e    = r * 256 + t;
        const int half = e >> 9;
        const int l    = (e >> 3) & 63;
        const int j    = e & 7;
        const int krow = half * 16 + ((l >> 5) << 3) + j;
        const int n    = l & 31;
        w2p[k * 1024 + e] = (f16)w2[k * (FOUT * FOUT) + krow * FOUT + n];
    }
}

// ---------------------------------------------------------------------------
// Dispatch 1: conv1 (EXACT round-1 body, part of the proven 173.5 µs config)
// + w2 packing fused as 27 extra blocks (saves one dispatch + its gap).
// h = silu(bn1(einsum(x_feats[nbr_idx], w1))) -> [N,32] f16
// ---------------------------------------------------------------------------
__global__ __launch_bounds__(256) void conv1_pack_kernel(
    const float* __restrict__ x_feats,   // [N,3]
    const int*   __restrict__ nbr_idx,   // [N,27]
    const float* __restrict__ w1,        // [27,3,32]
    const float* __restrict__ g1,  const float* __restrict__ b1,
    const float* __restrict__ m1,  const float* __restrict__ v1,
    f16* __restrict__ h_out,             // [N,32] f16
    const float* __restrict__ w2, f16* __restrict__ w2p)
{
    if (blockIdx.x >= NN / 256) {        // tail blocks: pack w2 tap
        pack_w2_block(w2, w2p, blockIdx.x - NN / 256, threadIdx.x);
        return;
    }
    const int n = blockIdx.x * 256 + threadIdx.x;

    int idxs[KK];
    const int* nb = nbr_idx + (size_t)n * KK;
#pragma unroll
    for (int k = 0; k < KK; ++k) idxs[k] = nb[k];   // break idx->gather chain

    float acc[FOUT];
#pragma unroll
    for (int o = 0; o < FOUT; ++o) acc[o] = 0.f;

#pragma unroll
    for (int c = 0; c < 3; ++c) {                   // 3 chunks of 9 neighbors
        float xs[9][3];
#pragma unroll
        for (int q = 0; q < 9; ++q) {               // 27 loads in flight
            const float* xr = x_feats + (size_t)idxs[c * 9 + q] * FIN;
            xs[q][0] = xr[0]; xs[q][1] = xr[1]; xs[q][2] = xr[2];
        }
#pragma unroll
        for (int q = 0; q < 9; ++q) {
            const float* w = w1 + (c * 9 + q) * (FIN * FOUT); // uniform->s_load
#pragma unroll
            for (int o = 0; o < FOUT; ++o) {
                float a = acc[o];
                a = fmaf(xs[q][0], w[o],            a);
                a = fmaf(xs[q][1], w[FOUT + o],     a);
                a = fmaf(xs[q][2], w[2 * FOUT + o], a);
                acc[o] = a;
            }
        }
    }

    f16* hr = h_out + (size_t)n * FOUT;
#pragma unroll
    for (int g = 0; g < 4; ++g) {
        f16x8 hv;
#pragma unroll
        for (int j = 0; j < 8; ++j) {
            const int o = g * 8 + j;
            const float sc = g1[o] * rsqrtf(v1[o] + EPS);
            float v = (acc[o] - m1[o]) * sc + b1[o];
            v = v / (1.f + __expf(-v));              // silu
            hv[j] = (f16)v;
        }
        *(f16x8*)(hr + g * 8) = hv;                  // 16B stores
    }
}

// ---------------------------------------------------------------------------
// Dispatch 2 (MFMA): x_out = einsum(h[nbr_idx], w2) + fused point branch.
// THE EXPERIMENT: asm-forced 6-slot gather window. Every prior C++ prefetch
// window was sunk by the compiler (VGPR 48/68/64 proved it) -> each wave had
// only ~2-4 scattered loads in flight vs ~600 cy latency. Here the 4 loads
// per tap (a1,a2,b1,b2) are issued with inline-asm global_load_dwordx4 and
// consumed under counted s_waitcnt vmcnt(N) (never 0 in steady state), with
// sched_barrier(0) after each wait (rule #18: stops MFMA hoisting past it).
// Steady state: 20-24 loads in flight per wave; vmcnt drains 20->0 in tail.
// ---------------------------------------------------------------------------
__global__ __launch_bounds__(256) void conv2_mfma_kernel(
    const f16*   __restrict__ h,         // [N,32] f16
    const int*   __restrict__ nbr_idx,   // [N,27]
    const f16*   __restrict__ w2p,       // packed [27][2][64][8] f16
    const float* __restrict__ z_feats,   // [N,3]
    const float* __restrict__ mlp_w,     // [3,32]
    const float* __restrict__ mlp_b,
    const float* __restrict__ mg, const float* __restrict__ mbe,
    const float* __restrict__ mm, const float* __restrict__ mv,
    float* __restrict__ out)             // [2,N,32]
{
    const int lane = threadIdx.x & 63;
    const int wave = threadIdx.x >> 6;
    const int base = (blockIdx.x * 4 + wave) * 32;   // this wave's node base
    const int row  = lane & 31;                      // A row
    const int hi   = lane >> 5;                      // contraction half of 8

    int idxs[KK];
    const int* nb = nbr_idx + (size_t)(base + row) * KK;
#pragma unroll
    for (int k = 0; k < KK; ++k) idxs[k] = nb[k];
#pragma unroll
    for (int k = 0; k < KK; ++k) asm volatile("" : "+v"(idxs[k]));

    f32x16 acc0 = {};                                // feats [0,16) partial
    f32x16 acc1 = {};                                // feats [16,32) partial

    // w2p element layout: k*1024 + half*512 + lane*8 (+j)
    f32x4 wa1[6], wa2[6], wb1[6], wb2[6];            // 6-slot rolling window

#define C2_ISSUE(t, s) do {                                                  \
        const f16* hr_ = h + (size_t)idxs[t] * FOUT + hi * 8;                \
        const f16* bb_ = w2p + (t) * 1024 + lane * 8;                        \
        asm volatile("global_load_dwordx4 %0, %1, off"                       \
                     : "=v"(wa1[s]) : "v"(hr_));                             \
        asm volatile("global_load_dwordx4 %0, %1, off"                       \
                     : "=v"(wa2[s]) : "v"(hr_ + 16));                        \
        asm volatile("global_load_dwordx4 %0, %1, off"                       \
                     : "=v"(wb1[s]) : "v"(bb_));                             \
        asm volatile("global_load_dwordx4 %0, %1, off"                       \
                     : "=v"(wb2[s]) : "v"(bb_ + 512));                       \
    } while (0)

#pragma unroll
    for (int t = 0; t < 6; ++t) C2_ISSUE(t, t);      // prologue: 24 in flight

#pragma unroll
    for (int k = 0; k < KK; ++k) {                   // fully unrolled: k const
        const int rem = KK - 1 - k;                  // taps issued after k
        if      (rem >= 5) asm volatile("s_waitcnt vmcnt(20)");
        else if (rem == 4) asm volatile("s_waitcnt vmcnt(16)");
        else if (rem == 3) asm volatile("s_waitcnt vmcnt(12)");
        else if (rem == 2) asm volatile("s_waitcnt vmcnt(8)");
        else if (rem == 1) asm volatile("s_waitcnt vmcnt(4)");
        else               asm volatile("s_waitcnt vmcnt(0)");
        __builtin_amdgcn_sched_barrier(0);           // rule #18: pin the wait

        const int s = k % 6;
        const f16x8 a1 = __builtin_bit_cast(f16x8, wa1[s]);
        const f16x8 a2 = __builtin_bit_cast(f16x8, wa2[s]);
        const f16x8 b1 = __builtin_bit_cast(f16x8, wb1[s]);
        const f16x8 b2 = __builtin_bit_cast(f16x8, wb2[s]);
        __builtin_amdgcn_s_setprio(1);
        acc0 = __builtin_amdgcn_mfma_f32_32x32x16_f16(a1, b1, acc0, 0, 0, 0);
        acc1 = __builtin_amdgcn_mfma_f32_32x32x16_f16(a2, b2, acc1, 0, 0, 0);
        __builtin_amdgcn_s_setprio(0);

        if (k + 6 < KK) C2_ISSUE(k + 6, s);          // refill freed slot
    }
#undef C2_ISSUE

    // ---- epilogue: point branch for output column n0, fused add + store ----
    const int n0 = lane & 31;
    const float wc0 = mlp_w[n0];
    const float wc1 = mlp_w[FOUT + n0];
    const float wc2 = mlp_w[2 * FOUT + n0];
    const float sc  = mg[n0] * rsqrtf(mv[n0] + EPS);
    const float bi  = mlp_b[n0];
    const float mmv = mm[n0];
    const float mbv = mbe[n0];

#pragma unroll
    for (int r = 0; r < 16; ++r) {
        const int m    = (r & 3) + ((r >> 2) << 3) + (hi << 2); // C/D row map
        const int node = base + m;
        const float* zr = z_feats + (size_t)node * FIN;
        float z = bi;
        z = fmaf(zr[0], wc0, z);
        z = fmaf(zr[1], wc1, z);
        z = fmaf(zr[2], wc2, z);
        z = (z - mmv) * sc + mbv;
        z = fmaxf(z, 0.f);
        const float v = acc0[r] + acc1[r] + z;
        out[(size_t)node * FOUT + n0] = v;
        out[(size_t)NN * FOUT + (size_t)node * FOUT + n0] = v;
    }
}

extern "C" void kernel_launch(void* const* d_in, const int* in_sizes, int n_in,
                              void* d_out, int out_size, void* d_ws, size_t ws_size,
                              hipStream_t stream) {
    const float* x_feats = (const float*)d_in[0];
    const float* z_feats = (const float*)d_in[1];
    const int*   nbr_idx = (const int*)d_in[2];
    const float* w1      = (const float*)d_in[3];
    const float* bn1_g   = (const float*)d_in[4];
    const float* bn1_b   = (const float*)d_in[5];
    const float* bn1_m   = (const float*)d_in[6];
    const float* bn1_v   = (const float*)d_in[7];
    const float* w2      = (const float*)d_in[8];
    const float* mlp_w   = (const float*)d_in[9];
    const float* mlp_b   = (const float*)d_in[10];
    const float* mlp_g   = (const float*)d_in[11];
    const float* mlp_be  = (const float*)d_in[12];
    const float* mlp_m   = (const float*)d_in[13];
    const float* mlp_v   = (const float*)d_in[14];

    // workspace: h [0, 8M)   w2p [8M, 8M+55296)
    f16* h   = (f16*)d_ws;
    f16* w2p = (f16*)((char*)d_ws + (size_t)8 * 1024 * 1024);
    float* out = (float*)d_out;

    conv1_pack_kernel<<<NN / 256 + KK, 256, 0, stream>>>(
        x_feats, nbr_idx, w1, bn1_g, bn1_b, bn1_m, bn1_v, h, w2, w2p);
    conv2_mfma_kernel<<<NN / 128, 256, 0, stream>>>(
        h, nbr_idx, w2p, z_feats, mlp_w, mlp_b, mlp_g, mlp_be,
        mlp_m, mlp_v, out);
}